// Round 3
// baseline (1343.884 us; speedup 1.0000x reference)
//
#include <hip/hip_runtime.h>

// out[o] = dot(in[o*I ..], W[(o&(M-1))*I ..]) + bias[o&(M-1)]
// B=1024, M=2048, I=128 (fp32). Memory-bound: stream 1 GiB of inputs once.
// W (1 MiB) + bias (8 KiB) must stay L2/L3-resident -> input loads are
// nontemporal. Register double-buffer keeps 8 float4 loads in flight
// across the shuffle-reduction phase.

typedef float fvec4 __attribute__((ext_vector_type(4)));  // native vector: OK for nontemporal builtins

constexpr int Mm = 2048;
constexpr int Ii = 128;
constexpr long long TOTAL = 1024LL * 2048;     // 2^21 output elements

constexpr int BLOCK = 256;                     // 4 waves
constexpr int GRID  = 8192;                    // 32768 waves
constexpr int WAVES = GRID * (BLOCK / 64);
constexpr int EPW   = (int)(TOTAL / WAVES);    // 64 elements per wave
constexpr int PAIRS = 4;                       // 8 elements per stage
constexpr int STEPS = EPW / (2 * PAIRS);       // 8 stages

__global__ __launch_bounds__(BLOCK, 4)
void diag_dot_kernel(const float* __restrict__ in,
                     const float* __restrict__ W,
                     const float* __restrict__ bias,
                     float* __restrict__ out) {
    const int tid  = blockIdx.x * BLOCK + threadIdx.x;
    const int wave = tid >> 6;
    const int lane = threadIdx.x & 63;
    const int half = lane >> 5;   // which element of the pair this lane covers
    const int sub  = lane & 31;   // float4 slot within the 128-float row

    const long long base = (long long)wave * EPW;

    fvec4 x[2][PAIRS], w[2][PAIRS];

    auto load_stage = [&](int s, int buf) {
#pragma unroll
        for (int j = 0; j < PAIRS; ++j) {
            const long long o = base + (long long)s * (2 * PAIRS) + 2 * j + half;
            const int m = (int)(o & (Mm - 1));
            const fvec4* ip = (const fvec4*)(in + o * Ii) + sub;
            const fvec4* wp = (const fvec4*)(W + (long long)m * Ii) + sub;
            x[buf][j] = __builtin_nontemporal_load(ip);  // streaming: don't evict W
            w[buf][j] = *wp;                             // temporal: keep in L2/L3
        }
    };

    load_stage(0, 0);

#pragma unroll
    for (int s = 0; s < STEPS; ++s) {
        const int cur = s & 1;
        const int nxt = cur ^ 1;
        if (s + 1 < STEPS) load_stage(s + 1, nxt);   // prefetch during reduction

#pragma unroll
        for (int j = 0; j < PAIRS; ++j) {
            const long long o = base + (long long)s * (2 * PAIRS) + 2 * j + half;
            float acc = x[cur][j].x * w[cur][j].x + x[cur][j].y * w[cur][j].y
                      + x[cur][j].z * w[cur][j].z + x[cur][j].w * w[cur][j].w;
            // reduce across the 32-lane half-wave (xor masks < 32 stay in-group)
            acc += __shfl_xor(acc, 16);
            acc += __shfl_xor(acc, 8);
            acc += __shfl_xor(acc, 4);
            acc += __shfl_xor(acc, 2);
            acc += __shfl_xor(acc, 1);
            if (sub == 0) {
                const int m = (int)(o & (Mm - 1));
                __builtin_nontemporal_store(acc + bias[m], out + o);
            }
        }
    }
}

extern "C" void kernel_launch(void* const* d_in, const int* in_sizes, int n_in,
                              void* d_out, int out_size, void* d_ws, size_t ws_size,
                              hipStream_t stream) {
    const float* in   = (const float*)d_in[0];   // (B, M, I) fp32
    const float* W    = (const float*)d_in[1];   // (M, I) fp32
    const float* bias = (const float*)d_in[2];   // (M,) fp32
    float* out = (float*)d_out;                  // (B, M) fp32

    diag_dot_kernel<<<GRID, BLOCK, 0, stream>>>(in, W, bias, out);
}